// Round 13
// baseline (248.650 us; speedup 1.0000x reference)
//
#include <hip/hip_runtime.h>
#include <hip/hip_bf16.h>
#include <stdint.h>

#define NN 4096
#define CS 2048           // chain size (NN / CHAINS)
#define KNN 20
#define LRK 40
#define EPN 60
#define SPHC 35
#define BBCC 32
#define NHEAD 8
#define HVD 64
#define HCD 32
#define LT 9
#define MAXC 384
#define VMB ((NN*LT)/4)   // vmat blocks = 2304
#define NPB (NN/8)        // nodeproj blocks = 512

#define INVAL_D2 0xFFFFFFFEu
#define CONSUMED 0xFFFFFFFFu

__device__ __forceinline__ float bflo(uint32_t d) { return __uint_as_float(d << 16); }
__device__ __forceinline__ float bfhi(uint32_t d) { return __uint_as_float(d & 0xFFFF0000u); }

__device__ __forceinline__ float fast_exp(float x) {
  return __builtin_amdgcn_exp2f(x * 1.4426950408889634f);
}
__device__ __forceinline__ float fast_cos(float a) {
  float rev = a * 0.15915494309189535f;
  rev = rev - __builtin_rintf(rev);
  return __builtin_amdgcn_cosf(rev);
}
__device__ __forceinline__ float fast_sin(float a) {
  float rev = a * 0.15915494309189535f;
  rev = rev - __builtin_rintf(rev);
  return __builtin_amdgcn_sinf(rev);
}

// ---- threefry2x32(key=[0,1]) -> -log(u); u bit-exact, log via v_log_f32 ----
__device__ __forceinline__ float neglogu_f(int i, int j) {
  uint32_t c = ((uint32_t)(i & 2047) << 12) | (uint32_t)j;
  const uint32_t ks0 = 0u, ks1 = 1u, ks2 = 0x1BD11BDBu;
  uint32_t x0 = c + ks0;
  uint32_t x1 = (c + 0x800000u) + ks1;
#define TF_R(r) { x0 += x1; x1 = (x1 << (r)) | (x1 >> (32 - (r))); x1 ^= x0; }
  TF_R(13) TF_R(15) TF_R(26) TF_R(6)   x0 += ks1; x1 += ks2 + 1u;
  TF_R(17) TF_R(29) TF_R(16) TF_R(24)  x0 += ks2; x1 += ks0 + 2u;
  TF_R(13) TF_R(15) TF_R(26) TF_R(6)   x0 += ks0; x1 += ks1 + 3u;
  TF_R(17) TF_R(29) TF_R(16) TF_R(24)  x0 += ks1; x1 += ks2 + 4u;
  TF_R(13) TF_R(15) TF_R(26) TF_R(6)   x0 += ks2; x1 += ks0 + 5u;
#undef TF_R
  uint32_t b = (i >= 2048) ? x1 : x0;
  float u = __uint_as_float((b >> 9) | 0x3F800000u) - 1.0f;
  u = u + 1.17549435e-38f;
  return -0.6931471805599453f * __builtin_amdgcn_logf(u);   // -ln(u) > 0
}

// ---- exact k-smallest pick over val[0..CS) using prebuilt 1024-bucket hist ----
// Emits sel[base..base+k) = cb + pos of the k lex-smallest (key,pos).
__device__ __forceinline__ void pick(const uint32_t* val, const uint32_t* hist,
                                     uint32_t* candk, uint32_t* candp,
                                     uint32_t* sh, int* sel,
                                     int k, int base, int cb, int tid) {
  if (tid == 0) { sh[2] = 0; sh[3] = 0; }
  // bucket-find: thread t owns buckets [4t, 4t+4)
  uint32_t h0 = hist[4*tid], h1 = hist[4*tid+1], h2 = hist[4*tid+2], h3 = hist[4*tid+3];
  uint32_t s = h0 + h1 + h2 + h3;
  uint32_t cum = s;
  #pragma unroll
  for (int off = 1; off < 64; off <<= 1) {
    uint32_t o = __shfl_up(cum, off, 64);
    if ((tid & 63) >= off) cum += o;
  }
  if ((tid & 63) == 63) sh[4 + (tid >> 6)] = cum;
  __syncthreads();
  uint32_t woff = 0;
  for (int w = 0; w < (tid >> 6); w++) woff += sh[4 + w];
  uint32_t cumAll = cum + woff;
  uint32_t cumBefore = cumAll - s;
  uint32_t rk = (uint32_t)k;
  if (rk > cumBefore && rk <= cumAll) {       // exactly one thread
    uint32_t r0 = rk - cumBefore, d, sub;
    if (r0 <= h0)            { d = 0; sub = 0; }
    else if (r0 <= h0+h1)    { d = 1; sub = h0; }
    else if (r0 <= h0+h1+h2) { d = 2; sub = h0 + h1; }
    else                     { d = 3; sub = h0 + h1 + h2; }
    sh[0] = 4u*tid + d;
    sh[1] = r0 - sub;
  }
  __syncthreads();
  const uint32_t B = sh[0], r = sh[1];
  // single scan: emit bucket<B (guaranteed in top-k), collect bucket==B
  #pragma unroll
  for (int q = 0; q < 8; q++) {
    int pos = tid + (q << 8);
    uint32_t key = val[pos];
    uint32_t b = key >> 22;
    if (b < B) {
      uint32_t slot = atomicAdd(&sh[2], 1u);
      sel[base + (int)slot] = cb + pos;
    } else if (b == B) {
      uint32_t idx = atomicAdd(&sh[3], 1u);
      if (idx < MAXC) { candk[idx] = key; candp[idx] = (uint32_t)pos; }
    }
  }
  __syncthreads();
  int m = (int)sh[3]; if (m > MAXC) m = MAXC;
  if (tid < 64) {                              // wave0: exact r-th by (key,pos) lex
    for (int ci = tid; ci < m; ci += 64) {
      unsigned long long k64 = ((unsigned long long)candk[ci] << 32) | candp[ci];
      uint32_t rank = 0;
      for (int j = 0; j < m; j++) {
        unsigned long long o = ((unsigned long long)candk[j] << 32) | candp[j];
        rank += (o < k64) ? 1u : 0u;
      }
      if (rank == r - 1) { sh[0] = candk[ci]; sh[1] = candp[ci]; }
    }
  }
  __syncthreads();
  const uint32_t vstar = sh[0], istar = sh[1];
  if (tid < 64) {                              // append the r bucket-B winners
    for (int ci = tid; ci < m; ci += 64) {
      uint32_t ck = candk[ci], cp = candp[ci];
      if (ck < vstar || (ck == vstar && cp <= istar)) {
        uint32_t slot = atomicAdd(&sh[2], 1u);
        sel[base + (int)slot] = cb + (int)cp;
      }
    }
  }
  __syncthreads();
}

// ---- Launch 1: select (0..4095) + vmat (4096..6399) + nodeproj (6400..6911) ----
__global__ __launch_bounds__(256) void graph_kernel(const float* __restrict__ X,
                                                    const int* __restrict__ batch,
                                                    const int* __restrict__ xmask,
                                                    const int* __restrict__ nmask,
                                                    const float* __restrict__ bbf,
                                                    const float* __restrict__ bbrel,
                                                    const float* __restrict__ wv,
                                                    const float* __restrict__ bv,
                                                    const float* __restrict__ w1,
                                                    const float* __restrict__ b1,
                                                    int* __restrict__ srcO,
                                                    __hip_bfloat16* __restrict__ V,
                                                    float* __restrict__ Pn,
                                                    float* __restrict__ Pd) {
#pragma clang fp contract(off)
  const int tid = threadIdx.x;
  if (blockIdx.x >= NN + VMB) {      // ---- nodeproj ----
    int t = tid & 31;
    int n = (blockIdx.x - NN - VMB) * 8 + (tid >> 5);
    float bv_ = bbf[(size_t)n * (LT*BBCC) + t];
    float an = 0.f, ad = b1[t];
    #pragma unroll 8
    for (int c = 0; c < BBCC; c++) {
      float bc = __shfl(bv_, (tid & 32) + c, 64);
      an = fmaf(bc, w1[c * HCD + t], an);
      ad = fmaf(bc, w1[(SPHC + c) * HCD + t], ad);
    }
    float nm = nmask[n] ? 1.f : 0.f;
    an = fmaf(nm, w1[34 * HCD + t], an);
    ad = fmaf(nm, w1[69 * HCD + t], ad);
    Pn[n * HCD + t] = an;
    Pd[n * HCD + t] = ad;
    return;
  }
  if (blockIdx.x >= NN) {            // ---- vmat (bf16 out) ----
    int row = (blockIdx.x - NN) * 4 + (tid >> 6);
    int d = tid & 63;
    int n = row / LT, l = row % LT;
    int li = (l == 0) ? 0 : (l < 4 ? 1 : 2);
    const float* w = wv + (size_t)li * SPHC * HVD;
    float acc = (l == 0) ? bv[d] : 0.f;
    const float* nb = bbf + (size_t)(n*LT + l) * BBCC;
    for (int c = 0; c < BBCC; c++) acc = fmaf(nb[c], w[c*HVD + d], acc);
    if (l >= 1 && l < 4) {
      for (int b = 0; b < 3; b++)
        acc = fmaf(bbrel[(size_t)(n*3 + b)*3 + (l-1)], w[(32+b)*HVD + d], acc);
    }
    if (l == 0) acc = fmaf(nmask[n] ? 1.f : 0.f, w[34*HVD + d], acc);
    V[(size_t)row * HVD + d] = __float2bfloat16(acc);
    return;
  }
  // ---- select ----
  __shared__ uint32_t valD[CS];      // 8KB d2 keys
  __shared__ uint32_t valW[CS];      // 8KB score keys
  __shared__ uint32_t histD[1024];   // 4KB
  __shared__ uint32_t histW[1024];   // 4KB
  __shared__ uint32_t candk[MAXC];
  __shared__ uint32_t candp[MAXC];
  __shared__ uint32_t sh[8];
  __shared__ int sel[EPN];
  const int i = blockIdx.x;

  if (xmask[i]) {                    // masked row: global tie-pool -> indices 0..k-1
    if (tid < KNN) srcO[(size_t)i * EPN + tid] = tid;
    else if (tid < EPN) srcO[(size_t)i * EPN + tid] = tid - KNN;
    return;
  }
  const int cb = batch[i] * CS;
  const float xi0 = X[i*3+0], xi1 = X[i*3+1], xi2 = X[i*3+2];
  const float x2i = (xi0*xi0 + xi1*xi1) + xi2*xi2;

  {  // zero both histograms
    uint4* hD = (uint4*)histD; uint4* hW = (uint4*)histW;
    uint4 z; z.x = 0; z.y = 0; z.z = 0; z.w = 0;
    hD[tid] = z; hW[tid] = z;
  }
  __syncthreads();

  // fused pass: d2 key + score key + both histograms (8 independent threefry chains)
  #pragma unroll
  for (int q = 0; q < 8; q++) {
    int pos = tid + (q << 8);
    int j = cb + pos;
    float xj0 = X[j*3+0], xj1 = X[j*3+1], xj2 = X[j*3+2];
    float x2j = (xj0*xj0 + xj1*xj1) + xj2*xj2;
    bool inval = (xmask[j] != 0) || (j == i);
    float dot = xi0*xj0 + xi1*xj1 + xi2*xj2;
    float d2r = (x2i + x2j) - 2.0f*dot;
    float d2 = d2r > 0.0f ? d2r : 0.0f;
    if (inval) {
      valD[pos] = INVAL_D2;          // bucket 1023: never reaches a pick scan
      valW[pos] = CONSUMED;
    } else {
      uint32_t kd = __float_as_uint(d2);
      valD[pos] = kd;
      atomicAdd(&histD[kd >> 22], 1u);
      float d2p = d2 + 1e-6f;
      float w = d2p * sqrtf(d2p) * neglogu_f(i, j);  // ascending w == descending score
      uint32_t kw = __float_as_uint(w);
      valW[pos] = kw;
      atomicAdd(&histW[kw >> 22], 1u);
    }
  }
  __syncthreads();

  pick(valD, histD, candk, candp, sh, sel, KNN, 0, cb, tid);

  // fixup: remove the 20 knn winners from the score pool
  if (tid < KNN) {
    int pos = sel[tid] - cb;
    uint32_t kw = valW[pos];
    atomicSub(&histW[kw >> 22], 1u);
    valW[pos] = CONSUMED;
  }
  __syncthreads();

  pick(valW, histW, candk, candp, sh, sel, LRK, KNN, cb, tid);

  if (tid < EPN) srcO[(size_t)i * EPN + tid] = sel[tid];
}

// ---- Launch 2: edge MLP -> logits (8 edges/block); fast transcendentals ----
__global__ __launch_bounds__(256) void edge_kernel(const int* __restrict__ src,
                                                   const float* __restrict__ X,
                                                   const float* __restrict__ Pn,
                                                   const float* __restrict__ Pd,
                                                   const float* __restrict__ w1,
                                                   const float* __restrict__ w2,
                                                   const float* __restrict__ b2,
                                                   float* __restrict__ logitO) {
  const float FR[8] = {1.0f, 0.31622776601683794f, 0.1f, 0.031622776601683794f,
                       0.01f, 0.0031622776601683794f, 0.001f, 0.00031622776601683794f};
  __shared__ float w1cf[BBCC][HCD];
  __shared__ float w2f[HCD][NHEAD];
  __shared__ float b2f[NHEAD];
  __shared__ float ef[8][BBCC];
  __shared__ float hbuf[8][HCD];
  int tid = threadIdx.x;
  for (int q = tid; q < BBCC*HCD; q += 256) w1cf[q >> 5][q & 31] = w1[70*HCD + q];
  if (tid < HCD*NHEAD) w2f[tid >> 3][tid & 7] = w2[tid];
  if (tid < NHEAD) b2f[tid] = b2[tid];
  int sub = tid >> 5, t = tid & 31;
  int e = blockIdx.x * 8 + sub;
  int d = e / EPN;
  int s = src[e];
  float dx = X[s*3+0] - X[d*3+0];
  float dy = X[s*3+1] - X[d*3+1];
  float dz = X[s*3+2] - X[d*3+2];
  float dist = sqrtf(dx*dx + dy*dy + dz*dz);
  if (t < 16) {
    float mu = (20.0f / 15.0f) * (float)t;
    float zz = (dist - mu) / 1.25f;
    ef[sub][t] = fast_exp(-zz * zz);
  } else {
    int k = t - 16;
    float del = (float)(s - d);
    float a = del * FR[k & 7];
    ef[sub][t] = (k < 8) ? fast_cos(a) : fast_sin(a);
  }
  __syncthreads();
  float a = Pn[s * HCD + t] + Pd[d * HCD + t];
  #pragma unroll
  for (int k = 0; k < BBCC; k++) a = fmaf(ef[sub][k], w1cf[k][t], a);
  hbuf[sub][t] = a / (1.f + fast_exp(-a));  // silu
  __syncthreads();
  if (tid < 64) {
    int e2 = tid >> 3, hh = tid & 7;
    float lg = b2f[hh];
    #pragma unroll
    for (int c = 0; c < HCD; c++) lg = fmaf(hbuf[e2][c], w2f[c][hh], lg);
    logitO[(size_t)(blockIdx.x * 8 + e2) * NHEAD + hh] = lg;
  }
}

// ---- Launch 3: softmax + single-wave dword-pair bf16 gather + SO3 epilogue ----
__global__ __launch_bounds__(64) void node_kernel(const int* __restrict__ src,
                                                  const float* __restrict__ logit,
                                                  const __hip_bfloat16* __restrict__ V,
                                                  const float* __restrict__ wo,
                                                  const float* __restrict__ bo,
                                                  const float* __restrict__ wg,
                                                  const float* __restrict__ bg,
                                                  const float* __restrict__ wf,
                                                  const float* __restrict__ bfb,
                                                  const float* __restrict__ w_xca,
                                                  const float* __restrict__ w_gate,
                                                  const float* __restrict__ b_gate,
                                                  const float* __restrict__ w_bb,
                                                  const float* __restrict__ X,
                                                  const float* __restrict__ bbrel,
                                                  const int* __restrict__ nmask,
                                                  float* __restrict__ out) {
  const int n = blockIdx.x, t = threadIdx.x;
  __shared__ float alpha[EPN][NHEAD];
  __shared__ int slist[EPN];
  __shared__ float agg[LT][HVD];
  __shared__ float o0[LT][BBCC];
  __shared__ float ofin[LT][BBCC];
  __shared__ float gate[BBCC];
  if (t < EPN) slist[t] = src[(size_t)n * EPN + t];
  for (int q = t; q < EPN * NHEAD; q += 64) alpha[q >> 3][q & 7] = logit[(size_t)n * 480 + q];
  __syncthreads();
  if (t < NHEAD) {
    float m = -1e30f;
    for (int e = 0; e < EPN; e++) m = fmaxf(m, alpha[e][t]);
    float Z = 0.f;
    for (int e = 0; e < EPN; e++) { float p = expf(alpha[e][t] - m); alpha[e][t] = p; Z += p; }
    float iz = 1.f / (Z + 1e-9f);
    for (int e = 0; e < EPN; e++) alpha[e][t] *= iz;
  }
  __syncthreads();
  {
    // lane t owns dwords {t, t+64, t+128, t+192} (+t+256 if t<32) of the 288-dword row.
    const int h = (t & 31) >> 2;
    const bool tail = (t < 32);
    float a0 = 0.f, a1 = 0.f, a2 = 0.f, a3 = 0.f, a4 = 0.f;
    float b0 = 0.f, b1_ = 0.f, b2_ = 0.f, b3 = 0.f, b4 = 0.f;
    #pragma unroll 4
    for (int e = 0; e < EPN; e++) {
      const uint32_t* Vr = (const uint32_t*)(V + (size_t)slist[e] * (LT * HVD));
      uint32_t d0 = Vr[t];
      uint32_t d1 = Vr[t + 64];
      uint32_t d2 = Vr[t + 128];
      uint32_t d3 = Vr[t + 192];
      uint32_t d4 = tail ? Vr[t + 256] : 0u;
      float a = alpha[e][h];
      a0 = fmaf(a, bflo(d0), a0);  b0  = fmaf(a, bfhi(d0), b0);
      a1 = fmaf(a, bflo(d1), a1);  b1_ = fmaf(a, bfhi(d1), b1_);
      a2 = fmaf(a, bflo(d2), a2);  b2_ = fmaf(a, bfhi(d2), b2_);
      a3 = fmaf(a, bflo(d3), a3);  b3  = fmaf(a, bfhi(d3), b3);
      a4 = fmaf(a, bflo(d4), a4);  b4  = fmaf(a, bfhi(d4), b4);
    }
    const int l0 = t >> 5, c = 2 * (t & 31);
    agg[l0 + 0][c] = a0;  agg[l0 + 0][c + 1] = b0;
    agg[l0 + 2][c] = a1;  agg[l0 + 2][c + 1] = b1_;
    agg[l0 + 4][c] = a2;  agg[l0 + 4][c + 1] = b2_;
    agg[l0 + 6][c] = a3;  agg[l0 + 6][c + 1] = b3;
    if (tail) { agg[8][c] = a4;  agg[8][c + 1] = b4; }
  }
  __syncthreads();
  for (int idx = t; idx < LT * BBCC; idx += 64) {
    int l = idx >> 5, d = idx & 31;
    int li = (l == 0) ? 0 : (l < 4 ? 1 : 2);
    float a = (l == 0) ? bo[d] : 0.f;
    const float* w = wo + (size_t)li * HVD * BBCC;
    for (int c = 0; c < HVD; c++) a = fmaf(agg[l][c], w[c * BBCC + d], a);
    o0[l][d] = a;
  }
  __syncthreads();
  if (t < BBCC) {
    float a = bg[t];
    for (int c = 0; c < BBCC; c++) a = fmaf(o0[0][c], wg[c * BBCC + t], a);
    gate[t] = a / (1.f + expf(-a));
  }
  __syncthreads();
  for (int idx = t; idx < LT * BBCC; idx += 64) {
    int l = idx >> 5, d = idx & 31;
    int li = (l == 0) ? 0 : (l < 4 ? 1 : 2);
    float a = (l == 0) ? bfb[d] : 0.f;
    const float* w = wf + (size_t)li * BBCC * BBCC;
    for (int c = 0; c < BBCC; c++) a = fmaf(o0[l][c], w[c * BBCC + d], a);
    float r = o0[l][d] + a * gate[d];
    ofin[l][d] = r;
    out[49152 + (size_t)n * 288 + idx] = r;
  }
  __syncthreads();
  if (t < 16) {
    float a2 = b_gate[0];
    for (int c = 0; c < BBCC; c++) a2 = fmaf(ofin[0][c], w_gate[c], a2);
    float g2 = fmaxf(a2, 0.f) + log1pf(expf(-fabsf(a2)));
    bool noise = nmask[n] != 0;
    if (t < 3) {
      float a = 0.f;
      for (int d2 = 0; d2 < BBCC; d2++) a = fmaf(ofin[1 + t][d2], w_xca[32 + d2], a);
      float nx = X[n * 3 + t] + (noise ? a * g2 : 0.f);
      out[(size_t)n * 3 + t] = nx;
    }
    if (t < 9) {
      int b = t / 3, c = t % 3;
      float a = 0.f;
      for (int d2 = 0; d2 < BBCC; d2++) a = fmaf(ofin[1 + c][d2], w_bb[(32 + d2) * 3 + b], a);
      float nb = bbrel[(size_t)(n * 3 + b) * 3 + c] + (noise ? a : 0.f);
      out[12288 + (size_t)n * 9 + b * 3 + c] = nb;
    }
  }
}

extern "C" void kernel_launch(void* const* d_in, const int* in_sizes, int n_in,
                              void* d_out, int out_size, void* d_ws, size_t ws_size,
                              hipStream_t stream) {
  (void)in_sizes; (void)n_in; (void)out_size;
  const float* X      = (const float*)d_in[0];
  const float* bbrel  = (const float*)d_in[1];
  const float* bbf    = (const float*)d_in[2];
  const int* batch    = (const int*)d_in[3];
  const int* xmask    = (const int*)d_in[4];
  const int* nmask    = (const int*)d_in[5];
  const float* w1     = (const float*)d_in[6];
  const float* b1     = (const float*)d_in[7];
  const float* w2     = (const float*)d_in[8];
  const float* b2     = (const float*)d_in[9];
  const float* wv     = (const float*)d_in[10];
  const float* bv     = (const float*)d_in[11];
  const float* wo     = (const float*)d_in[12];
  const float* bo     = (const float*)d_in[13];
  const float* wg     = (const float*)d_in[14];
  const float* bg     = (const float*)d_in[15];
  const float* wf     = (const float*)d_in[16];
  const float* bfb    = (const float*)d_in[17];
  const float* w_xca  = (const float*)d_in[18];
  const float* w_gate = (const float*)d_in[20];
  const float* b_gate = (const float*)d_in[21];
  const float* w_bb   = (const float*)d_in[22];

  if (ws_size < 18939904) return;
  char* ws = (char*)d_ws;
  int*      srcl  = (int*)(ws + 0);                    // 983,040
  float*    logit = (float*)(ws + 983040);             // 7,864,320 -> 8,847,360
  __hip_bfloat16* V = (__hip_bfloat16*)(ws + 8847360); // 4,718,592 -> 13,565,952
  float*    Pn    = (float*)(ws + 13565952);           // 524,288 -> 14,090,240
  float*    Pd    = (float*)(ws + 14090240);           // 524,288 -> 14,614,528
  float*    out   = (float*)d_out;

  graph_kernel<<<NN + VMB + NPB, 256, 0, stream>>>(X, batch, xmask, nmask, bbf, bbrel,
                                                   wv, bv, w1, b1, srcl, V, Pn, Pd);
  edge_kernel<<<(NN * EPN) / 8, 256, 0, stream>>>(srcl, X, Pn, Pd, w1, w2, b2, logit);
  node_kernel<<<NN, 64, 0, stream>>>(srcl, logit, V, wo, bo, wg, bg, wf, bfb,
                                     w_xca, w_gate, b_gate, w_bb, X, bbrel, nmask, out);
}

// Round 14
// 248.212 us; speedup vs baseline: 1.0018x; 1.0018x over previous
//
#include <hip/hip_runtime.h>
#include <hip/hip_bf16.h>
#include <stdint.h>

#define NN 4096
#define CS 2048           // chain size (NN / CHAINS)
#define KNN 20
#define LRK 40
#define EPN 60
#define SPHC 35
#define BBCC 32
#define NHEAD 8
#define HVD 64
#define HCD 32
#define LT 9
#define MAXC 384
#define VMB ((NN*LT)/4)   // vmat blocks = 2304
#define NPB (NN/8)        // nodeproj blocks = 512

#define INVAL_D2 0xFFFFFFFEu
#define CONSUMED 0xFFFFFFFFu

__device__ __forceinline__ float bflo(uint32_t d) { return __uint_as_float(d << 16); }
__device__ __forceinline__ float bfhi(uint32_t d) { return __uint_as_float(d & 0xFFFF0000u); }

__device__ __forceinline__ float fast_exp(float x) {
  return __builtin_amdgcn_exp2f(x * 1.4426950408889634f);
}
__device__ __forceinline__ float fast_cos(float a) {
  float rev = a * 0.15915494309189535f;
  rev = rev - __builtin_rintf(rev);
  return __builtin_amdgcn_cosf(rev);
}
__device__ __forceinline__ float fast_sin(float a) {
  float rev = a * 0.15915494309189535f;
  rev = rev - __builtin_rintf(rev);
  return __builtin_amdgcn_sinf(rev);
}

// ---- threefry2x32(key=[0,1]) -> -log(u); u bit-exact, log via v_log_f32 ----
__device__ __forceinline__ float neglogu_f(int i, int j) {
  uint32_t c = ((uint32_t)(i & 2047) << 12) | (uint32_t)j;
  const uint32_t ks0 = 0u, ks1 = 1u, ks2 = 0x1BD11BDBu;
  uint32_t x0 = c + ks0;
  uint32_t x1 = (c + 0x800000u) + ks1;
#define TF_R(r) { x0 += x1; x1 = (x1 << (r)) | (x1 >> (32 - (r))); x1 ^= x0; }
  TF_R(13) TF_R(15) TF_R(26) TF_R(6)   x0 += ks1; x1 += ks2 + 1u;
  TF_R(17) TF_R(29) TF_R(16) TF_R(24)  x0 += ks2; x1 += ks0 + 2u;
  TF_R(13) TF_R(15) TF_R(26) TF_R(6)   x0 += ks0; x1 += ks1 + 3u;
  TF_R(17) TF_R(29) TF_R(16) TF_R(24)  x0 += ks1; x1 += ks2 + 4u;
  TF_R(13) TF_R(15) TF_R(26) TF_R(6)   x0 += ks2; x1 += ks0 + 5u;
#undef TF_R
  uint32_t b = (i >= 2048) ? x1 : x0;
  float u = __uint_as_float((b >> 9) | 0x3F800000u) - 1.0f;
  u = u + 1.17549435e-38f;
  return -0.6931471805599453f * __builtin_amdgcn_logf(u);   // -ln(u) > 0
}

// ---- exact k-smallest pick over val[0..CS) using packed 16-bit 1024-bucket hist ----
// histp: 512 dwords, bucket b count = (histp[b>>1] >> ((b&1)*16)) & 0xFFFF.
// Emits sel[base..base+k) = cb + pos of the k lex-smallest (key,pos).
__device__ __forceinline__ void pick(const uint32_t* val, const uint32_t* histp,
                                     uint32_t* candk, uint32_t* candp,
                                     uint32_t* sh, int* sel,
                                     int k, int base, int cb, int tid) {
  if (tid == 0) { sh[2] = 0; sh[3] = 0; }
  // bucket-find: thread t owns buckets [4t, 4t+4) = packed words [2t, 2t+1]
  uint32_t w0 = histp[2*tid], w1 = histp[2*tid+1];
  uint32_t h0 = w0 & 0xFFFFu, h1 = w0 >> 16, h2 = w1 & 0xFFFFu, h3 = w1 >> 16;
  uint32_t s = h0 + h1 + h2 + h3;
  uint32_t cum = s;
  #pragma unroll
  for (int off = 1; off < 64; off <<= 1) {
    uint32_t o = __shfl_up(cum, off, 64);
    if ((tid & 63) >= off) cum += o;
  }
  if ((tid & 63) == 63) sh[4 + (tid >> 6)] = cum;
  __syncthreads();
  uint32_t woff = 0;
  for (int w = 0; w < (tid >> 6); w++) woff += sh[4 + w];
  uint32_t cumAll = cum + woff;
  uint32_t cumBefore = cumAll - s;
  uint32_t rk = (uint32_t)k;
  if (rk > cumBefore && rk <= cumAll) {       // exactly one thread
    uint32_t r0 = rk - cumBefore, d, sub;
    if (r0 <= h0)            { d = 0; sub = 0; }
    else if (r0 <= h0+h1)    { d = 1; sub = h0; }
    else if (r0 <= h0+h1+h2) { d = 2; sub = h0 + h1; }
    else                     { d = 3; sub = h0 + h1 + h2; }
    sh[0] = 4u*tid + d;
    sh[1] = r0 - sub;
  }
  __syncthreads();
  const uint32_t B = sh[0], r = sh[1];
  // single scan: emit bucket<B (guaranteed in top-k), collect bucket==B
  #pragma unroll
  for (int q = 0; q < 8; q++) {
    int pos = tid + (q << 8);
    uint32_t key = val[pos];
    uint32_t b = key >> 22;
    if (b < B) {
      uint32_t slot = atomicAdd(&sh[2], 1u);
      sel[base + (int)slot] = cb + pos;
    } else if (b == B) {
      uint32_t idx = atomicAdd(&sh[3], 1u);
      if (idx < MAXC) { candk[idx] = key; candp[idx] = (uint32_t)pos; }
    }
  }
  __syncthreads();
  int m = (int)sh[3]; if (m > MAXC) m = MAXC;
  // all 256 threads: exact r-th by (key,pos) lex
  for (int ci = tid; ci < m; ci += 256) {
    unsigned long long k64 = ((unsigned long long)candk[ci] << 32) | candp[ci];
    uint32_t rank = 0;
    for (int j = 0; j < m; j++) {
      unsigned long long o = ((unsigned long long)candk[j] << 32) | candp[j];
      rank += (o < k64) ? 1u : 0u;
    }
    if (rank == r - 1) { sh[0] = candk[ci]; sh[1] = candp[ci]; }
  }
  __syncthreads();
  const uint32_t vstar = sh[0], istar = sh[1];
  for (int ci = tid; ci < m; ci += 256) {     // append the r bucket-B winners
    uint32_t ck = candk[ci], cp = candp[ci];
    if (ck < vstar || (ck == vstar && cp <= istar)) {
      uint32_t slot = atomicAdd(&sh[2], 1u);
      sel[base + (int)slot] = cb + (int)cp;
    }
  }
  __syncthreads();
}

// ---- Launch 1: select (0..4095) + vmat (4096..6399) + nodeproj (6400..6911) ----
__global__ __launch_bounds__(256) void graph_kernel(const float* __restrict__ X,
                                                    const int* __restrict__ batch,
                                                    const int* __restrict__ xmask,
                                                    const int* __restrict__ nmask,
                                                    const float* __restrict__ bbf,
                                                    const float* __restrict__ bbrel,
                                                    const float* __restrict__ wv,
                                                    const float* __restrict__ bv,
                                                    const float* __restrict__ w1,
                                                    const float* __restrict__ b1,
                                                    int* __restrict__ srcO,
                                                    __hip_bfloat16* __restrict__ V,
                                                    float* __restrict__ Pn,
                                                    float* __restrict__ Pd) {
#pragma clang fp contract(off)
  const int tid = threadIdx.x;
  if (blockIdx.x >= NN + VMB) {      // ---- nodeproj ----
    int t = tid & 31;
    int n = (blockIdx.x - NN - VMB) * 8 + (tid >> 5);
    float bv_ = bbf[(size_t)n * (LT*BBCC) + t];
    float an = 0.f, ad = b1[t];
    #pragma unroll 8
    for (int c = 0; c < BBCC; c++) {
      float bc = __shfl(bv_, (tid & 32) + c, 64);
      an = fmaf(bc, w1[c * HCD + t], an);
      ad = fmaf(bc, w1[(SPHC + c) * HCD + t], ad);
    }
    float nm = nmask[n] ? 1.f : 0.f;
    an = fmaf(nm, w1[34 * HCD + t], an);
    ad = fmaf(nm, w1[69 * HCD + t], ad);
    Pn[n * HCD + t] = an;
    Pd[n * HCD + t] = ad;
    return;
  }
  if (blockIdx.x >= NN) {            // ---- vmat (bf16 out) ----
    int row = (blockIdx.x - NN) * 4 + (tid >> 6);
    int d = tid & 63;
    int n = row / LT, l = row % LT;
    int li = (l == 0) ? 0 : (l < 4 ? 1 : 2);
    const float* w = wv + (size_t)li * SPHC * HVD;
    float acc = (l == 0) ? bv[d] : 0.f;
    const float* nb = bbf + (size_t)(n*LT + l) * BBCC;
    for (int c = 0; c < BBCC; c++) acc = fmaf(nb[c], w[c*HVD + d], acc);
    if (l >= 1 && l < 4) {
      for (int b = 0; b < 3; b++)
        acc = fmaf(bbrel[(size_t)(n*3 + b)*3 + (l-1)], w[(32+b)*HVD + d], acc);
    }
    if (l == 0) acc = fmaf(nmask[n] ? 1.f : 0.f, w[34*HVD + d], acc);
    V[(size_t)row * HVD + d] = __float2bfloat16(acc);
    return;
  }
  // ---- select ----
  __shared__ uint32_t valD[CS];      // 8KB d2 keys
  __shared__ uint32_t valW[CS];      // 8KB score keys
  __shared__ uint32_t histD[512];    // 2KB (packed 16-bit x2)
  __shared__ uint32_t histW[512];    // 2KB
  __shared__ uint32_t candk[MAXC];
  __shared__ uint32_t candp[MAXC];
  __shared__ uint32_t sh[8];
  __shared__ int sel[EPN];
  const int i = blockIdx.x;

  if (xmask[i]) {                    // masked row: global tie-pool -> indices 0..k-1
    if (tid < KNN) srcO[(size_t)i * EPN + tid] = tid;
    else if (tid < EPN) srcO[(size_t)i * EPN + tid] = tid - KNN;
    return;
  }
  const int cb = batch[i] * CS;
  const float xi0 = X[i*3+0], xi1 = X[i*3+1], xi2 = X[i*3+2];
  const float x2i = (xi0*xi0 + xi1*xi1) + xi2*xi2;

  {  // zero both packed histograms (512 dwords each)
    uint2 z; z.x = 0; z.y = 0;
    ((uint2*)histD)[tid] = z;
    ((uint2*)histW)[tid] = z;
  }
  __syncthreads();

  // fused pass: d2 key + score key + both histograms (8 independent threefry chains)
  #pragma unroll
  for (int q = 0; q < 8; q++) {
    int pos = tid + (q << 8);
    int j = cb + pos;
    float xj0 = X[j*3+0], xj1 = X[j*3+1], xj2 = X[j*3+2];
    float x2j = (xj0*xj0 + xj1*xj1) + xj2*xj2;
    bool inval = (xmask[j] != 0) || (j == i);
    float dot = xi0*xj0 + xi1*xj1 + xi2*xj2;
    float d2r = (x2i + x2j) - 2.0f*dot;
    float d2 = d2r > 0.0f ? d2r : 0.0f;
    if (inval) {
      valD[pos] = INVAL_D2;          // bucket 1023: never reaches a pick scan
      valW[pos] = CONSUMED;
    } else {
      uint32_t kd = __float_as_uint(d2);
      valD[pos] = kd;
      atomicAdd(&histD[kd >> 23], ((kd >> 22) & 1u) ? 0x10000u : 1u);
      float d2p = d2 + 1e-6f;
      float w = d2p * sqrtf(d2p) * neglogu_f(i, j);  // ascending w == descending score
      uint32_t kw = __float_as_uint(w);
      valW[pos] = kw;
      atomicAdd(&histW[kw >> 23], ((kw >> 22) & 1u) ? 0x10000u : 1u);
    }
  }
  __syncthreads();

  pick(valD, histD, candk, candp, sh, sel, KNN, 0, cb, tid);

  // fixup: remove the 20 knn winners from the score pool
  if (tid < KNN) {
    int pos = sel[tid] - cb;
    uint32_t kw = valW[pos];
    atomicSub(&histW[kw >> 23], ((kw >> 22) & 1u) ? 0x10000u : 1u);
    valW[pos] = CONSUMED;
  }
  __syncthreads();

  pick(valW, histW, candk, candp, sh, sel, LRK, KNN, cb, tid);

  if (tid < EPN) srcO[(size_t)i * EPN + tid] = sel[tid];
}

// ---- Launch 2: edge MLP -> logits (8 edges/block); fast transcendentals ----
__global__ __launch_bounds__(256) void edge_kernel(const int* __restrict__ src,
                                                   const float* __restrict__ X,
                                                   const float* __restrict__ Pn,
                                                   const float* __restrict__ Pd,
                                                   const float* __restrict__ w1,
                                                   const float* __restrict__ w2,
                                                   const float* __restrict__ b2,
                                                   float* __restrict__ logitO) {
  const float FR[8] = {1.0f, 0.31622776601683794f, 0.1f, 0.031622776601683794f,
                       0.01f, 0.0031622776601683794f, 0.001f, 0.00031622776601683794f};
  __shared__ float w1cf[BBCC][HCD];
  __shared__ float w2f[HCD][NHEAD];
  __shared__ float b2f[NHEAD];
  __shared__ float ef[8][BBCC];
  __shared__ float hbuf[8][HCD];
  int tid = threadIdx.x;
  for (int q = tid; q < BBCC*HCD; q += 256) w1cf[q >> 5][q & 31] = w1[70*HCD + q];
  if (tid < HCD*NHEAD) w2f[tid >> 3][tid & 7] = w2[tid];
  if (tid < NHEAD) b2f[tid] = b2[tid];
  int sub = tid >> 5, t = tid & 31;
  int e = blockIdx.x * 8 + sub;
  int d = e / EPN;
  int s = src[e];
  float dx = X[s*3+0] - X[d*3+0];
  float dy = X[s*3+1] - X[d*3+1];
  float dz = X[s*3+2] - X[d*3+2];
  float dist = sqrtf(dx*dx + dy*dy + dz*dz);
  if (t < 16) {
    float mu = (20.0f / 15.0f) * (float)t;
    float zz = (dist - mu) / 1.25f;
    ef[sub][t] = fast_exp(-zz * zz);
  } else {
    int k = t - 16;
    float del = (float)(s - d);
    float a = del * FR[k & 7];
    ef[sub][t] = (k < 8) ? fast_cos(a) : fast_sin(a);
  }
  __syncthreads();
  float a = Pn[s * HCD + t] + Pd[d * HCD + t];
  #pragma unroll
  for (int k = 0; k < BBCC; k++) a = fmaf(ef[sub][k], w1cf[k][t], a);
  hbuf[sub][t] = a / (1.f + fast_exp(-a));  // silu
  __syncthreads();
  if (tid < 64) {
    int e2 = tid >> 3, hh = tid & 7;
    float lg = b2f[hh];
    #pragma unroll
    for (int c = 0; c < HCD; c++) lg = fmaf(hbuf[e2][c], w2f[c][hh], lg);
    logitO[(size_t)(blockIdx.x * 8 + e2) * NHEAD + hh] = lg;
  }
}

// ---- Launch 3: softmax + single-wave dword-pair bf16 gather + SO3 epilogue ----
__global__ __launch_bounds__(64) void node_kernel(const int* __restrict__ src,
                                                  const float* __restrict__ logit,
                                                  const __hip_bfloat16* __restrict__ V,
                                                  const float* __restrict__ wo,
                                                  const float* __restrict__ bo,
                                                  const float* __restrict__ wg,
                                                  const float* __restrict__ bg,
                                                  const float* __restrict__ wf,
                                                  const float* __restrict__ bfb,
                                                  const float* __restrict__ w_xca,
                                                  const float* __restrict__ w_gate,
                                                  const float* __restrict__ b_gate,
                                                  const float* __restrict__ w_bb,
                                                  const float* __restrict__ X,
                                                  const float* __restrict__ bbrel,
                                                  const int* __restrict__ nmask,
                                                  float* __restrict__ out) {
  const int n = blockIdx.x, t = threadIdx.x;
  __shared__ float alpha[EPN][NHEAD];
  __shared__ int slist[EPN];
  __shared__ float agg[LT][HVD];
  __shared__ float o0[LT][BBCC];
  __shared__ float ofin[LT][BBCC];
  __shared__ float gate[BBCC];
  if (t < EPN) slist[t] = src[(size_t)n * EPN + t];
  for (int q = t; q < EPN * NHEAD; q += 64) alpha[q >> 3][q & 7] = logit[(size_t)n * 480 + q];
  __syncthreads();
  if (t < NHEAD) {
    float m = -1e30f;
    for (int e = 0; e < EPN; e++) m = fmaxf(m, alpha[e][t]);
    float Z = 0.f;
    for (int e = 0; e < EPN; e++) { float p = expf(alpha[e][t] - m); alpha[e][t] = p; Z += p; }
    float iz = 1.f / (Z + 1e-9f);
    for (int e = 0; e < EPN; e++) alpha[e][t] *= iz;
  }
  __syncthreads();
  {
    // lane t owns dwords {t, t+64, t+128, t+192} (+t+256 if t<32) of the 288-dword row.
    const int h = (t & 31) >> 2;
    const bool tail = (t < 32);
    float a0 = 0.f, a1 = 0.f, a2 = 0.f, a3 = 0.f, a4 = 0.f;
    float b0 = 0.f, b1_ = 0.f, b2_ = 0.f, b3 = 0.f, b4 = 0.f;
    #pragma unroll 4
    for (int e = 0; e < EPN; e++) {
      const uint32_t* Vr = (const uint32_t*)(V + (size_t)slist[e] * (LT * HVD));
      uint32_t d0 = Vr[t];
      uint32_t d1 = Vr[t + 64];
      uint32_t d2 = Vr[t + 128];
      uint32_t d3 = Vr[t + 192];
      uint32_t d4 = tail ? Vr[t + 256] : 0u;
      float a = alpha[e][h];
      a0 = fmaf(a, bflo(d0), a0);  b0  = fmaf(a, bfhi(d0), b0);
      a1 = fmaf(a, bflo(d1), a1);  b1_ = fmaf(a, bfhi(d1), b1_);
      a2 = fmaf(a, bflo(d2), a2);  b2_ = fmaf(a, bfhi(d2), b2_);
      a3 = fmaf(a, bflo(d3), a3);  b3  = fmaf(a, bfhi(d3), b3);
      a4 = fmaf(a, bflo(d4), a4);  b4  = fmaf(a, bfhi(d4), b4);
    }
    const int l0 = t >> 5, c = 2 * (t & 31);
    agg[l0 + 0][c] = a0;  agg[l0 + 0][c + 1] = b0;
    agg[l0 + 2][c] = a1;  agg[l0 + 2][c + 1] = b1_;
    agg[l0 + 4][c] = a2;  agg[l0 + 4][c + 1] = b2_;
    agg[l0 + 6][c] = a3;  agg[l0 + 6][c + 1] = b3;
    if (tail) { agg[8][c] = a4;  agg[8][c + 1] = b4; }
  }
  __syncthreads();
  for (int idx = t; idx < LT * BBCC; idx += 64) {
    int l = idx >> 5, d = idx & 31;
    int li = (l == 0) ? 0 : (l < 4 ? 1 : 2);
    float a = (l == 0) ? bo[d] : 0.f;
    const float* w = wo + (size_t)li * HVD * BBCC;
    for (int c = 0; c < HVD; c++) a = fmaf(agg[l][c], w[c * BBCC + d], a);
    o0[l][d] = a;
  }
  __syncthreads();
  if (t < BBCC) {
    float a = bg[t];
    for (int c = 0; c < BBCC; c++) a = fmaf(o0[0][c], wg[c * BBCC + t], a);
    gate[t] = a / (1.f + expf(-a));
  }
  __syncthreads();
  for (int idx = t; idx < LT * BBCC; idx += 64) {
    int l = idx >> 5, d = idx & 31;
    int li = (l == 0) ? 0 : (l < 4 ? 1 : 2);
    float a = (l == 0) ? bfb[d] : 0.f;
    const float* w = wf + (size_t)li * BBCC * BBCC;
    for (int c = 0; c < BBCC; c++) a = fmaf(o0[l][c], w[c * BBCC + d], a);
    float r = o0[l][d] + a * gate[d];
    ofin[l][d] = r;
    out[49152 + (size_t)n * 288 + idx] = r;
  }
  __syncthreads();
  if (t < 16) {
    float a2 = b_gate[0];
    for (int c = 0; c < BBCC; c++) a2 = fmaf(ofin[0][c], w_gate[c], a2);
    float g2 = fmaxf(a2, 0.f) + log1pf(expf(-fabsf(a2)));
    bool noise = nmask[n] != 0;
    if (t < 3) {
      float a = 0.f;
      for (int d2 = 0; d2 < BBCC; d2++) a = fmaf(ofin[1 + t][d2], w_xca[32 + d2], a);
      float nx = X[n * 3 + t] + (noise ? a * g2 : 0.f);
      out[(size_t)n * 3 + t] = nx;
    }
    if (t < 9) {
      int b = t / 3, c = t % 3;
      float a = 0.f;
      for (int d2 = 0; d2 < BBCC; d2++) a = fmaf(ofin[1 + c][d2], w_bb[(32 + d2) * 3 + b], a);
      float nb = bbrel[(size_t)(n * 3 + b) * 3 + c] + (noise ? a : 0.f);
      out[12288 + (size_t)n * 9 + b * 3 + c] = nb;
    }
  }
}

extern "C" void kernel_launch(void* const* d_in, const int* in_sizes, int n_in,
                              void* d_out, int out_size, void* d_ws, size_t ws_size,
                              hipStream_t stream) {
  (void)in_sizes; (void)n_in; (void)out_size;
  const float* X      = (const float*)d_in[0];
  const float* bbrel  = (const float*)d_in[1];
  const float* bbf    = (const float*)d_in[2];
  const int* batch    = (const int*)d_in[3];
  const int* xmask    = (const int*)d_in[4];
  const int* nmask    = (const int*)d_in[5];
  const float* w1     = (const float*)d_in[6];
  const float* b1     = (const float*)d_in[7];
  const float* w2     = (const float*)d_in[8];
  const float* b2     = (const float*)d_in[9];
  const float* wv     = (const float*)d_in[10];
  const float* bv     = (const float*)d_in[11];
  const float* wo     = (const float*)d_in[12];
  const float* bo     = (const float*)d_in[13];
  const float* wg     = (const float*)d_in[14];
  const float* bg     = (const float*)d_in[15];
  const float* wf     = (const float*)d_in[16];
  const float* bfb    = (const float*)d_in[17];
  const float* w_xca  = (const float*)d_in[18];
  const float* w_gate = (const float*)d_in[20];
  const float* b_gate = (const float*)d_in[21];
  const float* w_bb   = (const float*)d_in[22];

  if (ws_size < 18939904) return;
  char* ws = (char*)d_ws;
  int*      srcl  = (int*)(ws + 0);                    // 983,040
  float*    logit = (float*)(ws + 983040);             // 7,864,320 -> 8,847,360
  __hip_bfloat16* V = (__hip_bfloat16*)(ws + 8847360); // 4,718,592 -> 13,565,952
  float*    Pn    = (float*)(ws + 13565952);           // 524,288 -> 14,090,240
  float*    Pd    = (float*)(ws + 14090240);           // 524,288 -> 14,614,528
  float*    out   = (float*)d_out;

  graph_kernel<<<NN + VMB + NPB, 256, 0, stream>>>(X, batch, xmask, nmask, bbf, bbrel,
                                                   wv, bv, w1, b1, srcl, V, Pn, Pd);
  edge_kernel<<<(NN * EPN) / 8, 256, 0, stream>>>(srcl, X, Pn, Pd, w1, w2, b2, logit);
  node_kernel<<<NN, 64, 0, stream>>>(srcl, logit, V, wo, bo, wg, bg, wf, bfb,
                                     w_xca, w_gate, b_gate, w_bb, X, bbrel, nmask, out);
}

// Round 15
// 246.581 us; speedup vs baseline: 1.0084x; 1.0066x over previous
//
#include <hip/hip_runtime.h>
#include <hip/hip_bf16.h>
#include <stdint.h>

#define NN 4096
#define CS 2048           // chain size (NN / CHAINS)
#define KNN 20
#define LRK 40
#define EPN 60
#define SPHC 35
#define BBCC 32
#define NHEAD 8
#define HVD 64
#define HCD 32
#define LT 9
#define MAXC 384
#define VMB ((NN*LT)/4)   // vmat blocks = 2304
#define NPB (NN/8)        // nodeproj blocks = 512

#define INVAL_D2 0xFFFFFFFEu
#define CONSUMED 0xFFFFFFFFu

__device__ __forceinline__ float bflo(uint32_t d) { return __uint_as_float(d << 16); }
__device__ __forceinline__ float bfhi(uint32_t d) { return __uint_as_float(d & 0xFFFF0000u); }

__device__ __forceinline__ float fast_exp(float x) {
  return __builtin_amdgcn_exp2f(x * 1.4426950408889634f);
}
__device__ __forceinline__ float fast_cos(float a) {
  float rev = a * 0.15915494309189535f;
  rev = rev - __builtin_rintf(rev);
  return __builtin_amdgcn_cosf(rev);
}
__device__ __forceinline__ float fast_sin(float a) {
  float rev = a * 0.15915494309189535f;
  rev = rev - __builtin_rintf(rev);
  return __builtin_amdgcn_sinf(rev);
}

// ---- threefry2x32(key=[0,1]) -> -log(u); u bit-exact, log via v_log_f32 ----
__device__ __forceinline__ float neglogu_f(int i, int j) {
  uint32_t c = ((uint32_t)(i & 2047) << 12) | (uint32_t)j;
  const uint32_t ks0 = 0u, ks1 = 1u, ks2 = 0x1BD11BDBu;
  uint32_t x0 = c + ks0;
  uint32_t x1 = (c + 0x800000u) + ks1;
#define TF_R(r) { x0 += x1; x1 = (x1 << (r)) | (x1 >> (32 - (r))); x1 ^= x0; }
  TF_R(13) TF_R(15) TF_R(26) TF_R(6)   x0 += ks1; x1 += ks2 + 1u;
  TF_R(17) TF_R(29) TF_R(16) TF_R(24)  x0 += ks2; x1 += ks0 + 2u;
  TF_R(13) TF_R(15) TF_R(26) TF_R(6)   x0 += ks0; x1 += ks1 + 3u;
  TF_R(17) TF_R(29) TF_R(16) TF_R(24)  x0 += ks1; x1 += ks2 + 4u;
  TF_R(13) TF_R(15) TF_R(26) TF_R(6)   x0 += ks2; x1 += ks0 + 5u;
#undef TF_R
  uint32_t b = (i >= 2048) ? x1 : x0;
  float u = __uint_as_float((b >> 9) | 0x3F800000u) - 1.0f;
  u = u + 1.17549435e-38f;
  return -0.6931471805599453f * __builtin_amdgcn_logf(u);   // -ln(u) > 0
}

// ---- exact k-smallest pick over val[0..CS) using 1024-bucket hist ----
// Emits sel[base..base+k) = cb + pos of the k lex-smallest (key,pos).
__device__ __forceinline__ void pick(const uint32_t* val, const uint32_t* hist,
                                     uint32_t* candk, uint32_t* candp,
                                     uint32_t* sh, int* sel,
                                     int k, int base, int cb, int tid) {
  if (tid == 0) { sh[2] = 0; sh[3] = 0; }
  // bucket-find: thread t owns buckets [4t, 4t+4)
  uint32_t h0 = hist[4*tid], h1 = hist[4*tid+1], h2 = hist[4*tid+2], h3 = hist[4*tid+3];
  uint32_t s = h0 + h1 + h2 + h3;
  uint32_t cum = s;
  #pragma unroll
  for (int off = 1; off < 64; off <<= 1) {
    uint32_t o = __shfl_up(cum, off, 64);
    if ((tid & 63) >= off) cum += o;
  }
  if ((tid & 63) == 63) sh[4 + (tid >> 6)] = cum;
  __syncthreads();
  uint32_t woff = 0;
  for (int w = 0; w < (tid >> 6); w++) woff += sh[4 + w];
  uint32_t cumAll = cum + woff;
  uint32_t cumBefore = cumAll - s;
  uint32_t rk = (uint32_t)k;
  if (rk > cumBefore && rk <= cumAll) {       // exactly one thread
    uint32_t r0 = rk - cumBefore, d, sub;
    if (r0 <= h0)            { d = 0; sub = 0; }
    else if (r0 <= h0+h1)    { d = 1; sub = h0; }
    else if (r0 <= h0+h1+h2) { d = 2; sub = h0 + h1; }
    else                     { d = 3; sub = h0 + h1 + h2; }
    sh[0] = 4u*tid + d;
    sh[1] = r0 - sub;
  }
  __syncthreads();
  const uint32_t B = sh[0], r = sh[1];
  // single scan: emit bucket<B (guaranteed in top-k), collect bucket==B
  #pragma unroll
  for (int q = 0; q < 8; q++) {
    int pos = tid + (q << 8);
    uint32_t key = val[pos];
    uint32_t b = key >> 22;
    if (b < B) {
      uint32_t slot = atomicAdd(&sh[2], 1u);
      sel[base + (int)slot] = cb + pos;
    } else if (b == B) {
      uint32_t idx = atomicAdd(&sh[3], 1u);
      if (idx < MAXC) { candk[idx] = key; candp[idx] = (uint32_t)pos; }
    }
  }
  __syncthreads();
  int m = (int)sh[3]; if (m > MAXC) m = MAXC;
  // all 256 threads: exact r-th by (key,pos) lex
  for (int ci = tid; ci < m; ci += 256) {
    unsigned long long k64 = ((unsigned long long)candk[ci] << 32) | candp[ci];
    uint32_t rank = 0;
    for (int j = 0; j < m; j++) {
      unsigned long long o = ((unsigned long long)candk[j] << 32) | candp[j];
      rank += (o < k64) ? 1u : 0u;
    }
    if (rank == r - 1) { sh[0] = candk[ci]; sh[1] = candp[ci]; }
  }
  __syncthreads();
  const uint32_t vstar = sh[0], istar = sh[1];
  for (int ci = tid; ci < m; ci += 256) {     // append the r bucket-B winners
    uint32_t ck = candk[ci], cp = candp[ci];
    if (ck < vstar || (ck == vstar && cp <= istar)) {
      uint32_t slot = atomicAdd(&sh[2], 1u);
      sel[base + (int)slot] = cb + (int)cp;
    }
  }
  __syncthreads();
}

// ---- Launch 1: select (0..4095) + vmat (4096..6399) + nodeproj (6400..6911) ----
__global__ __launch_bounds__(256) void graph_kernel(const float* __restrict__ X,
                                                    const int* __restrict__ batch,
                                                    const int* __restrict__ xmask,
                                                    const int* __restrict__ nmask,
                                                    const float* __restrict__ bbf,
                                                    const float* __restrict__ bbrel,
                                                    const float* __restrict__ wv,
                                                    const float* __restrict__ bv,
                                                    const float* __restrict__ w1,
                                                    const float* __restrict__ b1,
                                                    int* __restrict__ srcO,
                                                    __hip_bfloat16* __restrict__ V,
                                                    float* __restrict__ Pn,
                                                    float* __restrict__ Pd) {
#pragma clang fp contract(off)
  const int tid = threadIdx.x;
  if (blockIdx.x >= NN + VMB) {      // ---- nodeproj ----
    int t = tid & 31;
    int n = (blockIdx.x - NN - VMB) * 8 + (tid >> 5);
    float bv_ = bbf[(size_t)n * (LT*BBCC) + t];
    float an = 0.f, ad = b1[t];
    #pragma unroll 8
    for (int c = 0; c < BBCC; c++) {
      float bc = __shfl(bv_, (tid & 32) + c, 64);
      an = fmaf(bc, w1[c * HCD + t], an);
      ad = fmaf(bc, w1[(SPHC + c) * HCD + t], ad);
    }
    float nm = nmask[n] ? 1.f : 0.f;
    an = fmaf(nm, w1[34 * HCD + t], an);
    ad = fmaf(nm, w1[69 * HCD + t], ad);
    Pn[n * HCD + t] = an;
    Pd[n * HCD + t] = ad;
    return;
  }
  if (blockIdx.x >= NN) {            // ---- vmat (bf16 out) ----
    int row = (blockIdx.x - NN) * 4 + (tid >> 6);
    int d = tid & 63;
    int n = row / LT, l = row % LT;
    int li = (l == 0) ? 0 : (l < 4 ? 1 : 2);
    const float* w = wv + (size_t)li * SPHC * HVD;
    float acc = (l == 0) ? bv[d] : 0.f;
    const float* nb = bbf + (size_t)(n*LT + l) * BBCC;
    for (int c = 0; c < BBCC; c++) acc = fmaf(nb[c], w[c*HVD + d], acc);
    if (l >= 1 && l < 4) {
      for (int b = 0; b < 3; b++)
        acc = fmaf(bbrel[(size_t)(n*3 + b)*3 + (l-1)], w[(32+b)*HVD + d], acc);
    }
    if (l == 0) acc = fmaf(nmask[n] ? 1.f : 0.f, w[34*HVD + d], acc);
    V[(size_t)row * HVD + d] = __float2bfloat16(acc);
    return;
  }
  // ---- select ----
  __shared__ uint32_t valD[CS];      // 8KB d2 keys
  __shared__ uint32_t valW[CS];      // 8KB score keys
  __shared__ uint32_t histD[1024];   // 4KB
  __shared__ uint32_t histW[1024];   // 4KB
  __shared__ uint32_t candk[MAXC];
  __shared__ uint32_t candp[MAXC];
  __shared__ uint32_t sh[8];
  __shared__ int sel[EPN];
  const int i = blockIdx.x;

  if (xmask[i]) {                    // masked row: global tie-pool -> indices 0..k-1
    if (tid < KNN) srcO[(size_t)i * EPN + tid] = tid;
    else if (tid < EPN) srcO[(size_t)i * EPN + tid] = tid - KNN;
    return;
  }
  const int cb = batch[i] * CS;
  const float xi0 = X[i*3+0], xi1 = X[i*3+1], xi2 = X[i*3+2];
  const float x2i = (xi0*xi0 + xi1*xi1) + xi2*xi2;

  {  // zero both histograms
    uint4* hD = (uint4*)histD; uint4* hW = (uint4*)histW;
    uint4 z; z.x = 0; z.y = 0; z.z = 0; z.w = 0;
    hD[tid] = z; hW[tid] = z;
  }
  __syncthreads();

  // fused pass: d2 key + score key + both histograms (8 independent threefry chains)
  #pragma unroll
  for (int q = 0; q < 8; q++) {
    int pos = tid + (q << 8);
    int j = cb + pos;
    float xj0 = X[j*3+0], xj1 = X[j*3+1], xj2 = X[j*3+2];
    float x2j = (xj0*xj0 + xj1*xj1) + xj2*xj2;
    bool inval = (xmask[j] != 0) || (j == i);
    float dot = xi0*xj0 + xi1*xj1 + xi2*xj2;
    float d2r = (x2i + x2j) - 2.0f*dot;
    float d2 = d2r > 0.0f ? d2r : 0.0f;
    if (inval) {
      valD[pos] = INVAL_D2;          // bucket 1023: never reaches a pick scan
      valW[pos] = CONSUMED;
    } else {
      uint32_t kd = __float_as_uint(d2);
      valD[pos] = kd;
      atomicAdd(&histD[kd >> 22], 1u);
      float d2p = d2 + 1e-6f;
      float w = d2p * sqrtf(d2p) * neglogu_f(i, j);  // ascending w == descending score
      uint32_t kw = __float_as_uint(w);
      valW[pos] = kw;
      atomicAdd(&histW[kw >> 22], 1u);
    }
  }
  __syncthreads();

  pick(valD, histD, candk, candp, sh, sel, KNN, 0, cb, tid);

  // fixup: remove the 20 knn winners from the score pool
  if (tid < KNN) {
    int pos = sel[tid] - cb;
    uint32_t kw = valW[pos];
    atomicSub(&histW[kw >> 22], 1u);
    valW[pos] = CONSUMED;
  }
  __syncthreads();

  pick(valW, histW, candk, candp, sh, sel, LRK, KNN, cb, tid);

  if (tid < EPN) srcO[(size_t)i * EPN + tid] = sel[tid];
}

// ---- Launch 2: edge MLP -> logits (8 edges/block); fast transcendentals ----
__global__ __launch_bounds__(256) void edge_kernel(const int* __restrict__ src,
                                                   const float* __restrict__ X,
                                                   const float* __restrict__ Pn,
                                                   const float* __restrict__ Pd,
                                                   const float* __restrict__ w1,
                                                   const float* __restrict__ w2,
                                                   const float* __restrict__ b2,
                                                   float* __restrict__ logitO) {
  const float FR[8] = {1.0f, 0.31622776601683794f, 0.1f, 0.031622776601683794f,
                       0.01f, 0.0031622776601683794f, 0.001f, 0.00031622776601683794f};
  __shared__ float w1cf[BBCC][HCD];
  __shared__ float w2f[HCD][NHEAD];
  __shared__ float b2f[NHEAD];
  __shared__ float ef[8][BBCC];
  __shared__ float hbuf[8][HCD];
  int tid = threadIdx.x;
  for (int q = tid; q < BBCC*HCD; q += 256) w1cf[q >> 5][q & 31] = w1[70*HCD + q];
  if (tid < HCD*NHEAD) w2f[tid >> 3][tid & 7] = w2[tid];
  if (tid < NHEAD) b2f[tid] = b2[tid];
  int sub = tid >> 5, t = tid & 31;
  int e = blockIdx.x * 8 + sub;
  int d = e / EPN;
  int s = src[e];
  float dx = X[s*3+0] - X[d*3+0];
  float dy = X[s*3+1] - X[d*3+1];
  float dz = X[s*3+2] - X[d*3+2];
  float dist = sqrtf(dx*dx + dy*dy + dz*dz);
  if (t < 16) {
    float mu = (20.0f / 15.0f) * (float)t;
    float zz = (dist - mu) / 1.25f;
    ef[sub][t] = fast_exp(-zz * zz);
  } else {
    int k = t - 16;
    float del = (float)(s - d);
    float a = del * FR[k & 7];
    ef[sub][t] = (k < 8) ? fast_cos(a) : fast_sin(a);
  }
  __syncthreads();
  float a = Pn[s * HCD + t] + Pd[d * HCD + t];
  #pragma unroll
  for (int k = 0; k < BBCC; k++) a = fmaf(ef[sub][k], w1cf[k][t], a);
  hbuf[sub][t] = a / (1.f + fast_exp(-a));  // silu
  __syncthreads();
  if (tid < 64) {
    int e2 = tid >> 3, hh = tid & 7;
    float lg = b2f[hh];
    #pragma unroll
    for (int c = 0; c < HCD; c++) lg = fmaf(hbuf[e2][c], w2f[c][hh], lg);
    logitO[(size_t)(blockIdx.x * 8 + e2) * NHEAD + hh] = lg;
  }
}

// ---- Launch 3: softmax + single-wave dword-pair bf16 gather + SO3 epilogue ----
__global__ __launch_bounds__(64) void node_kernel(const int* __restrict__ src,
                                                  const float* __restrict__ logit,
                                                  const __hip_bfloat16* __restrict__ V,
                                                  const float* __restrict__ wo,
                                                  const float* __restrict__ bo,
                                                  const float* __restrict__ wg,
                                                  const float* __restrict__ bg,
                                                  const float* __restrict__ wf,
                                                  const float* __restrict__ bfb,
                                                  const float* __restrict__ w_xca,
                                                  const float* __restrict__ w_gate,
                                                  const float* __restrict__ b_gate,
                                                  const float* __restrict__ w_bb,
                                                  const float* __restrict__ X,
                                                  const float* __restrict__ bbrel,
                                                  const int* __restrict__ nmask,
                                                  float* __restrict__ out) {
  const int n = blockIdx.x, t = threadIdx.x;
  __shared__ float alpha[EPN][NHEAD];
  __shared__ int slist[EPN];
  __shared__ float agg[LT][HVD];
  __shared__ float o0[LT][BBCC];
  __shared__ float ofin[LT][BBCC];
  __shared__ float gate[BBCC];
  if (t < EPN) slist[t] = src[(size_t)n * EPN + t];
  for (int q = t; q < EPN * NHEAD; q += 64) alpha[q >> 3][q & 7] = logit[(size_t)n * 480 + q];
  __syncthreads();
  if (t < NHEAD) {
    float m = -1e30f;
    for (int e = 0; e < EPN; e++) m = fmaxf(m, alpha[e][t]);
    float Z = 0.f;
    for (int e = 0; e < EPN; e++) { float p = expf(alpha[e][t] - m); alpha[e][t] = p; Z += p; }
    float iz = 1.f / (Z + 1e-9f);
    for (int e = 0; e < EPN; e++) alpha[e][t] *= iz;
  }
  __syncthreads();
  {
    // lane t owns dwords {t, t+64, t+128, t+192} (+t+256 if t<32) of the 288-dword row.
    const int h = (t & 31) >> 2;
    const bool tail = (t < 32);
    float a0 = 0.f, a1 = 0.f, a2 = 0.f, a3 = 0.f, a4 = 0.f;
    float b0 = 0.f, b1_ = 0.f, b2_ = 0.f, b3 = 0.f, b4 = 0.f;
    #pragma unroll 4
    for (int e = 0; e < EPN; e++) {
      const uint32_t* Vr = (const uint32_t*)(V + (size_t)slist[e] * (LT * HVD));
      uint32_t d0 = Vr[t];
      uint32_t d1 = Vr[t + 64];
      uint32_t d2 = Vr[t + 128];
      uint32_t d3 = Vr[t + 192];
      uint32_t d4 = tail ? Vr[t + 256] : 0u;
      float a = alpha[e][h];
      a0 = fmaf(a, bflo(d0), a0);  b0  = fmaf(a, bfhi(d0), b0);
      a1 = fmaf(a, bflo(d1), a1);  b1_ = fmaf(a, bfhi(d1), b1_);
      a2 = fmaf(a, bflo(d2), a2);  b2_ = fmaf(a, bfhi(d2), b2_);
      a3 = fmaf(a, bflo(d3), a3);  b3  = fmaf(a, bfhi(d3), b3);
      a4 = fmaf(a, bflo(d4), a4);  b4  = fmaf(a, bfhi(d4), b4);
    }
    const int l0 = t >> 5, c = 2 * (t & 31);
    agg[l0 + 0][c] = a0;  agg[l0 + 0][c + 1] = b0;
    agg[l0 + 2][c] = a1;  agg[l0 + 2][c + 1] = b1_;
    agg[l0 + 4][c] = a2;  agg[l0 + 4][c + 1] = b2_;
    agg[l0 + 6][c] = a3;  agg[l0 + 6][c + 1] = b3;
    if (tail) { agg[8][c] = a4;  agg[8][c + 1] = b4; }
  }
  __syncthreads();
  for (int idx = t; idx < LT * BBCC; idx += 64) {
    int l = idx >> 5, d = idx & 31;
    int li = (l == 0) ? 0 : (l < 4 ? 1 : 2);
    float a = (l == 0) ? bo[d] : 0.f;
    const float* w = wo + (size_t)li * HVD * BBCC;
    for (int c = 0; c < HVD; c++) a = fmaf(agg[l][c], w[c * BBCC + d], a);
    o0[l][d] = a;
  }
  __syncthreads();
  if (t < BBCC) {
    float a = bg[t];
    for (int c = 0; c < BBCC; c++) a = fmaf(o0[0][c], wg[c * BBCC + t], a);
    gate[t] = a / (1.f + expf(-a));
  }
  __syncthreads();
  for (int idx = t; idx < LT * BBCC; idx += 64) {
    int l = idx >> 5, d = idx & 31;
    int li = (l == 0) ? 0 : (l < 4 ? 1 : 2);
    float a = (l == 0) ? bfb[d] : 0.f;
    const float* w = wf + (size_t)li * BBCC * BBCC;
    for (int c = 0; c < BBCC; c++) a = fmaf(o0[l][c], w[c * BBCC + d], a);
    float r = o0[l][d] + a * gate[d];
    ofin[l][d] = r;
    out[49152 + (size_t)n * 288 + idx] = r;
  }
  __syncthreads();
  if (t < 16) {
    float a2 = b_gate[0];
    for (int c = 0; c < BBCC; c++) a2 = fmaf(ofin[0][c], w_gate[c], a2);
    float g2 = fmaxf(a2, 0.f) + log1pf(expf(-fabsf(a2)));
    bool noise = nmask[n] != 0;
    if (t < 3) {
      float a = 0.f;
      for (int d2 = 0; d2 < BBCC; d2++) a = fmaf(ofin[1 + t][d2], w_xca[32 + d2], a);
      float nx = X[n * 3 + t] + (noise ? a * g2 : 0.f);
      out[(size_t)n * 3 + t] = nx;
    }
    if (t < 9) {
      int b = t / 3, c = t % 3;
      float a = 0.f;
      for (int d2 = 0; d2 < BBCC; d2++) a = fmaf(ofin[1 + c][d2], w_bb[(32 + d2) * 3 + b], a);
      float nb = bbrel[(size_t)(n * 3 + b) * 3 + c] + (noise ? a : 0.f);
      out[12288 + (size_t)n * 9 + b * 3 + c] = nb;
    }
  }
}

extern "C" void kernel_launch(void* const* d_in, const int* in_sizes, int n_in,
                              void* d_out, int out_size, void* d_ws, size_t ws_size,
                              hipStream_t stream) {
  (void)in_sizes; (void)n_in; (void)out_size;
  const float* X      = (const float*)d_in[0];
  const float* bbrel  = (const float*)d_in[1];
  const float* bbf    = (const float*)d_in[2];
  const int* batch    = (const int*)d_in[3];
  const int* xmask    = (const int*)d_in[4];
  const int* nmask    = (const int*)d_in[5];
  const float* w1     = (const float*)d_in[6];
  const float* b1     = (const float*)d_in[7];
  const float* w2     = (const float*)d_in[8];
  const float* b2     = (const float*)d_in[9];
  const float* wv     = (const float*)d_in[10];
  const float* bv     = (const float*)d_in[11];
  const float* wo     = (const float*)d_in[12];
  const float* bo     = (const float*)d_in[13];
  const float* wg     = (const float*)d_in[14];
  const float* bg     = (const float*)d_in[15];
  const float* wf     = (const float*)d_in[16];
  const float* bfb    = (const float*)d_in[17];
  const float* w_xca  = (const float*)d_in[18];
  const float* w_gate = (const float*)d_in[20];
  const float* b_gate = (const float*)d_in[21];
  const float* w_bb   = (const float*)d_in[22];

  if (ws_size < 18939904) return;
  char* ws = (char*)d_ws;
  int*      srcl  = (int*)(ws + 0);                    // 983,040
  float*    logit = (float*)(ws + 983040);             // 7,864,320 -> 8,847,360
  __hip_bfloat16* V = (__hip_bfloat16*)(ws + 8847360); // 4,718,592 -> 13,565,952
  float*    Pn    = (float*)(ws + 13565952);           // 524,288 -> 14,090,240
  float*    Pd    = (float*)(ws + 14090240);           // 524,288 -> 14,614,528
  float*    out   = (float*)d_out;

  graph_kernel<<<NN + VMB + NPB, 256, 0, stream>>>(X, batch, xmask, nmask, bbf, bbrel,
                                                   wv, bv, w1, b1, srcl, V, Pn, Pd);
  edge_kernel<<<(NN * EPN) / 8, 256, 0, stream>>>(srcl, X, Pn, Pd, w1, w2, b2, logit);
  node_kernel<<<NN, 64, 0, stream>>>(srcl, logit, V, wo, bo, wg, bg, wf, bfb,
                                     w_xca, w_gate, b_gate, w_bb, X, bbrel, nmask, out);
}